// Round 1
// baseline (132.334 us; speedup 1.0000x reference)
//
#include <hip/hip_runtime.h>

#define NB 16
#define NC 32
#define NX 48
#define NY 48
#define NZ 48
#define YZ (NY*NZ)          // 2304
#define XYZ (NX*NY*NZ)      // 110592
#define SUM_NUM 56623104.0  // 16*32*110592

struct Ws {
  double g_sum;
  double g_dis;
  double g_div;
  int amax[NB*NC];
};

// Pass 1: per-(b,c) block — global sum + first-occurrence argmax.
// Also folds in the analytic dz^2 term: X*Y * sum_z (mz - z)^2.
__global__ __launch_bounds__(1024) void k_sum_amax(const float* __restrict__ f,
                                                   Ws* __restrict__ ws) {
  const int bc = blockIdx.x;
  const float4* __restrict__ p = reinterpret_cast<const float4*>(f + (size_t)bc * XYZ);
  const int t = threadIdx.x;
  float bmax = -3.402823466e38f;
  int bidx = 0x7fffffff;
  float fsum = 0.f;
  for (int i = t; i < XYZ/4; i += 1024) {
    float4 v = p[i];
    fsum += (v.x + v.y) + (v.z + v.w);
    const int base = i << 2;
    if (v.x > bmax) { bmax = v.x; bidx = base;   }
    if (v.y > bmax) { bmax = v.y; bidx = base+1; }
    if (v.z > bmax) { bmax = v.z; bidx = base+2; }
    if (v.w > bmax) { bmax = v.w; bidx = base+3; }
  }
  __shared__ float sval[1024];
  __shared__ int   sidx[1024];
  __shared__ float ssum[1024];
  sval[t] = bmax; sidx[t] = bidx; ssum[t] = fsum;
  __syncthreads();
  for (int off = 512; off > 0; off >>= 1) {
    if (t < off) {
      ssum[t] += ssum[t+off];
      const float vo = sval[t+off]; const int io = sidx[t+off];
      // max value wins; ties -> smaller linear index (first occurrence)
      if (vo > sval[t] || (vo == sval[t] && io < sidx[t])) { sval[t] = vo; sidx[t] = io; }
    }
    __syncthreads();
  }
  if (t == 0) {
    atomicAdd(&ws->g_sum, (double)ssum[0]);
    const int idx = sidx[0];
    ws->amax[bc] = idx;
    const double mz = (double)(idx % NZ);
    // sum_{z=0}^{47} (mz - z)^2 = 48*mz^2 - 2*1128*mz + 35720
    const double dz2 = 48.0*mz*mz - 2256.0*mz + 35720.0;
    atomicAdd(&ws->g_dis, 2304.0 * dz2);  // scaled by X*Y
  }
}

// Pass 2: fused dis (main term) + div. One thread = 4 consecutive voxels
// (same x,y since Z=48 and quads are aligned). Single pass over channels:
//   dis  = SXX - 2x*SX - 2y*SY + (x^2+y^2)*S0      (SX=Σ sq*mx, etc.)
//   div  = (m1-mg)^2*(S0_v - m1^2) + (m2-mg)^2*m1^2   per voxel (top-2 trick)
__global__ __launch_bounds__(256) void k_main(const float* __restrict__ f,
                                              Ws* __restrict__ ws) {
  const int b    = blockIdx.x / 108;   // 108 blocks cover 110592 voxels (256*4 each)
  const int sblk = blockIdx.x % 108;
  const int t = threadIdx.x;
  __shared__ float smx[NC], smy[NC], smxy[NC];
  __shared__ double smgr;
  if (t < NC) {
    const int idx = ws->amax[b*NC + t];
    const float mx = (float)(idx / YZ);
    const float my = (float)((idx / NZ) % NY);
    smx[t] = mx; smy[t] = my; smxy[t] = mx*mx + my*my;
  }
  if (t == 0) smgr = ws->g_sum;
  __syncthreads();
  const float mg = (float)(smgr / SUM_NUM);

  const int s0 = sblk*1024 + t*4;
  const float x = (float)(s0 / YZ);
  const float y = (float)((s0 / NZ) % NY);
  const float4* __restrict__ p =
      reinterpret_cast<const float4*>(f + (size_t)b*NC*XYZ + s0);

  const float NEG = -3.402823466e38f;
  float4 m1 = make_float4(NEG,NEG,NEG,NEG);
  float4 m2 = make_float4(NEG,NEG,NEG,NEG);
  float4 S0 = make_float4(0.f,0.f,0.f,0.f);
  float SX = 0.f, SY = 0.f, SXX = 0.f;

  #pragma unroll
  for (int c = 0; c < NC; c++) {
    const float4 v = p[(size_t)c * (XYZ/4)];
    float4 sq;
    sq.x = v.x*v.x; sq.y = v.y*v.y; sq.z = v.z*v.z; sq.w = v.w*v.w;
    const float sqs = (sq.x+sq.y)+(sq.z+sq.w);
    S0.x += sq.x; S0.y += sq.y; S0.z += sq.z; S0.w += sq.w;
    SX  += sqs * smx[c];
    SY  += sqs * smy[c];
    SXX += sqs * smxy[c];
    if (v.x > m1.x) { m2.x = m1.x; m1.x = v.x; } else if (v.x > m2.x) m2.x = v.x;
    if (v.y > m1.y) { m2.y = m1.y; m1.y = v.y; } else if (v.y > m2.y) m2.y = v.y;
    if (v.z > m1.z) { m2.z = m1.z; m1.z = v.z; } else if (v.z > m2.z) m2.z = v.z;
    if (v.w > m1.w) { m2.w = m1.w; m1.w = v.w; } else if (v.w > m2.w) m2.w = v.w;
  }

  const float S0s = (S0.x + S0.y) + (S0.z + S0.w);
  float dis = SXX - 2.f*x*SX - 2.f*y*SY + (x*x + y*y)*S0s;

  float dv = 0.f;
  {
    float d1, d2, sq1;
    d1 = m1.x - mg; d2 = m2.x - mg; sq1 = m1.x*m1.x;
    dv += d1*d1*(S0.x - sq1) + d2*d2*sq1;
    d1 = m1.y - mg; d2 = m2.y - mg; sq1 = m1.y*m1.y;
    dv += d1*d1*(S0.y - sq1) + d2*d2*sq1;
    d1 = m1.z - mg; d2 = m2.z - mg; sq1 = m1.z*m1.z;
    dv += d1*d1*(S0.z - sq1) + d2*d2*sq1;
    d1 = m1.w - mg; d2 = m2.w - mg; sq1 = m1.w*m1.w;
    dv += d1*d1*(S0.w - sq1) + d2*d2*sq1;
  }

  // block reduce (wave64 shuffle + LDS across 4 waves)
  for (int off = 32; off > 0; off >>= 1) {
    dis += __shfl_down(dis, off);
    dv  += __shfl_down(dv,  off);
  }
  __shared__ float rdis[4], rdiv[4];
  const int wid = t >> 6, lane = t & 63;
  if (lane == 0) { rdis[wid] = dis; rdiv[wid] = dv; }
  __syncthreads();
  if (t == 0) {
    atomicAdd(&ws->g_dis, (double)((rdis[0]+rdis[1]) + (rdis[2]+rdis[3])));
    atomicAdd(&ws->g_div, (double)((rdiv[0]+rdiv[1]) + (rdiv[2]+rdiv[3])));
  }
}

__global__ void k_fin(const Ws* __restrict__ ws, float* __restrict__ out) {
  out[0] = (float)(ws->g_dis / SUM_NUM);
  out[1] = (float)(ws->g_div / SUM_NUM);
}

extern "C" void kernel_launch(void* const* d_in, const int* in_sizes, int n_in,
                              void* d_out, int out_size, void* d_ws, size_t ws_size,
                              hipStream_t stream) {
  const float* f = (const float*)d_in[0];
  Ws* ws = (Ws*)d_ws;
  float* out = (float*)d_out;
  // zero the three accumulators every call (ws is not re-poisoned between replays)
  hipMemsetAsync(d_ws, 0, 3*sizeof(double), stream);
  hipLaunchKernelGGL(k_sum_amax, dim3(NB*NC), dim3(1024), 0, stream, f, ws);
  hipLaunchKernelGGL(k_main,     dim3(NB*108), dim3(256), 0, stream, f, ws);
  hipLaunchKernelGGL(k_fin,      dim3(1),      dim3(1),   0, stream, ws, out);
}

// Round 2
// 77.174 us; speedup vs baseline: 1.7148x; 1.7148x over previous
//
#include <hip/hip_runtime.h>

#define NB 16
#define NC 32
#define NBC (NB*NC)         // 512
#define NX 48
#define NY 48
#define NZ 48
#define YZ (NY*NZ)          // 2304
#define XYZ (NX*NY*NZ)      // 110592
#define Q (XYZ/4)           // 27648 float4s per (b,c)
#define SUM_NUM 56623104.0  // 16*32*110592
#define K2_PER_B 108        // 108 blocks * 256 thr * 4 voxels = 110592
#define K2_BLOCKS (NB*K2_PER_B)

struct Ws {
  int   amax[NBC];
  float vsum[NBC];
  float S0[NBC];
  float Sx[NBC];
  float Sy[NBC];
  float Sq2[NBC];           // sum sq*(x^2+y^2)
  float pA[K2_BLOCKS];      // per-block sum sq*mo^2
  float pB[K2_BLOCKS];      // per-block sum sq*mo
};

// ---------------- Pass A: per-(b,c) argmax + spatial moments -------------
// One 1024-thread block per (b,c). No atomics; writes one record per bc.
__global__ __launch_bounds__(1024) void k_moments(const float* __restrict__ f,
                                                  Ws* __restrict__ ws) {
  const int bc = blockIdx.x;
  const float4* __restrict__ p = reinterpret_cast<const float4*>(f + (size_t)bc * XYZ);
  const int t = threadIdx.x;
  float bmax = -3.402823466e38f;
  int bidx = 0;
  float vs = 0.f, s0 = 0.f, sx = 0.f, sy = 0.f, sq2 = 0.f;
  for (int i = t; i < Q; i += 1024) {
    const float4 v = p[i];
    const int base = i << 2;          // linear voxel index; 4 voxels share (x,y)
    const int xi = i / 576;           // base/2304
    const int yi = (i / 12) % 48;     // (base/48)%48
    const float xf = (float)xi, yf = (float)yi;
    const float sq = (v.x*v.x + v.y*v.y) + (v.z*v.z + v.w*v.w);
    vs += (v.x + v.y) + (v.z + v.w);
    s0 += sq;
    sx  = fmaf(sq, xf, sx);
    sy  = fmaf(sq, yf, sy);
    sq2 = fmaf(sq, fmaf(xf, xf, yf*yf), sq2);
    if (v.x > bmax) { bmax = v.x; bidx = base;   }
    if (v.y > bmax) { bmax = v.y; bidx = base+1; }
    if (v.z > bmax) { bmax = v.z; bidx = base+2; }
    if (v.w > bmax) { bmax = v.w; bidx = base+3; }
  }
  // wave-level reduce (lane 0 result valid; classic descending-offset pattern)
  for (int off = 32; off > 0; off >>= 1) {
    vs  += __shfl_down(vs,  off);
    s0  += __shfl_down(s0,  off);
    sx  += __shfl_down(sx,  off);
    sy  += __shfl_down(sy,  off);
    sq2 += __shfl_down(sq2, off);
    const float ov = __shfl_down(bmax, off);
    const int   oi = __shfl_down(bidx, off);
    if (ov > bmax || (ov == bmax && oi < bidx)) { bmax = ov; bidx = oi; }
  }
  __shared__ float svs[16], ss0[16], ssx[16], ssy[16], ssq2[16], smx[16];
  __shared__ int   sbi[16];
  const int wid = t >> 6;
  if ((t & 63) == 0) {
    svs[wid] = vs; ss0[wid] = s0; ssx[wid] = sx; ssy[wid] = sy;
    ssq2[wid] = sq2; smx[wid] = bmax; sbi[wid] = bidx;
  }
  __syncthreads();
  if (t == 0) {
    for (int w = 1; w < 16; w++) {
      vs += svs[w]; s0 += ss0[w]; sx += ssx[w]; sy += ssy[w]; sq2 += ssq2[w];
      if (smx[w] > bmax || (smx[w] == bmax && sbi[w] < bidx)) { bmax = smx[w]; bidx = sbi[w]; }
    }
    ws->amax[bc] = bidx;
    ws->vsum[bc] = vs;
    ws->S0[bc]   = s0;
    ws->Sx[bc]   = sx;
    ws->Sy[bc]   = sy;
    ws->Sq2[bc]  = sq2;
  }
}

// ---------------- Pass B: per-voxel channel top-2 -> div moments ---------
// Independent of pass A (mgr folded in at finalize). One thread = 4 voxels.
__global__ __launch_bounds__(256) void k_top2(const float* __restrict__ f,
                                              Ws* __restrict__ ws) {
  const int b    = blockIdx.x / K2_PER_B;
  const int sblk = blockIdx.x % K2_PER_B;
  const int t = threadIdx.x;
  const float4* __restrict__ p =
      reinterpret_cast<const float4*>(f + (size_t)b * NC * XYZ) + (sblk * 256 + t);

  const float NEG = -3.402823466e38f;
  float4 m1 = make_float4(NEG,NEG,NEG,NEG);
  float4 m2 = make_float4(NEG,NEG,NEG,NEG);
  float4 s0 = make_float4(0.f,0.f,0.f,0.f);

  #pragma unroll 8
  for (int c = 0; c < NC; c++) {
    const float4 v = p[(size_t)c * Q];
    s0.x = fmaf(v.x, v.x, s0.x);
    s0.y = fmaf(v.y, v.y, s0.y);
    s0.z = fmaf(v.z, v.z, s0.z);
    s0.w = fmaf(v.w, v.w, s0.w);
    if (v.x > m1.x) { m2.x = m1.x; m1.x = v.x; } else if (v.x > m2.x) m2.x = v.x;
    if (v.y > m1.y) { m2.y = m1.y; m1.y = v.y; } else if (v.y > m2.y) m2.y = v.y;
    if (v.z > m1.z) { m2.z = m1.z; m1.z = v.z; } else if (v.z > m2.z) m2.z = v.z;
    if (v.w > m1.w) { m2.w = m1.w; m1.w = v.w; } else if (v.w > m2.w) m2.w = v.w;
  }

  // A = sum sq*mo^2, B = sum sq*mo ; mo = m1 except arg-channel (m2), sq_arg = m1^2
  float A = 0.f, Bv = 0.f;
  {
    float q1, rest;
    q1 = m1.x*m1.x; rest = s0.x - q1;
    A  = fmaf(q1, rest, A);  A  = fmaf(m2.x*m2.x, q1, A);
    Bv = fmaf(m1.x, rest, Bv); Bv = fmaf(m2.x, q1, Bv);
    q1 = m1.y*m1.y; rest = s0.y - q1;
    A  = fmaf(q1, rest, A);  A  = fmaf(m2.y*m2.y, q1, A);
    Bv = fmaf(m1.y, rest, Bv); Bv = fmaf(m2.y, q1, Bv);
    q1 = m1.z*m1.z; rest = s0.z - q1;
    A  = fmaf(q1, rest, A);  A  = fmaf(m2.z*m2.z, q1, A);
    Bv = fmaf(m1.z, rest, Bv); Bv = fmaf(m2.z, q1, Bv);
    q1 = m1.w*m1.w; rest = s0.w - q1;
    A  = fmaf(q1, rest, A);  A  = fmaf(m2.w*m2.w, q1, A);
    Bv = fmaf(m1.w, rest, Bv); Bv = fmaf(m2.w, q1, Bv);
  }

  for (int off = 32; off > 0; off >>= 1) {
    A  += __shfl_down(A,  off);
    Bv += __shfl_down(Bv, off);
  }
  __shared__ float rA[4], rB[4];
  const int wid = t >> 6;
  if ((t & 63) == 0) { rA[wid] = A; rB[wid] = Bv; }
  __syncthreads();
  if (t == 0) {
    ws->pA[blockIdx.x] = (rA[0] + rA[1]) + (rA[2] + rA[3]);
    ws->pB[blockIdx.x] = (rB[0] + rB[1]) + (rB[2] + rB[3]);
  }
}

// ---------------- Finalize: assemble both scalars in f64 -----------------
__global__ __launch_bounds__(512) void k_fin(const Ws* __restrict__ ws,
                                             float* __restrict__ out) {
  const int t = threadIdx.x;
  double dis, vs, c0, a = 0.0, bb = 0.0;
  {
    const int idx = ws->amax[t];
    const double mx = (double)(idx / YZ);
    const double my = (double)((idx / NZ) % NY);
    const double mz = (double)(idx % NZ);
    const double S0 = ws->S0[t], Sx = ws->Sx[t], Sy = ws->Sy[t], Sq2 = ws->Sq2[t];
    // sum over voxels of sq*((mx-x)^2+(my-y)^2), plus analytic X*Y*sum_z(mz-z)^2
    dis = Sq2 - 2.0*mx*Sx - 2.0*my*Sy + (mx*mx + my*my)*S0
        + 2304.0 * (48.0*mz*mz - 2256.0*mz + 35720.0);
    vs = ws->vsum[t];
    c0 = S0;
  }
  for (int i = t; i < K2_BLOCKS; i += 512) { a += ws->pA[i]; bb += ws->pB[i]; }

  for (int off = 32; off > 0; off >>= 1) {
    dis += __shfl_down(dis, off);
    vs  += __shfl_down(vs,  off);
    c0  += __shfl_down(c0,  off);
    a   += __shfl_down(a,   off);
    bb  += __shfl_down(bb,  off);
  }
  __shared__ double sd[8][5];
  const int wid = t >> 6;
  if ((t & 63) == 0) { sd[wid][0]=dis; sd[wid][1]=vs; sd[wid][2]=c0; sd[wid][3]=a; sd[wid][4]=bb; }
  __syncthreads();
  if (t == 0) {
    for (int w = 1; w < 8; w++) {
      dis += sd[w][0]; vs += sd[w][1]; c0 += sd[w][2]; a += sd[w][3]; bb += sd[w][4];
    }
    const double mgr = vs / SUM_NUM;
    out[0] = (float)(dis / SUM_NUM);
    out[1] = (float)((a - 2.0*mgr*bb + mgr*mgr*c0) / SUM_NUM);
  }
}

extern "C" void kernel_launch(void* const* d_in, const int* in_sizes, int n_in,
                              void* d_out, int out_size, void* d_ws, size_t ws_size,
                              hipStream_t stream) {
  const float* f = (const float*)d_in[0];
  Ws* ws = (Ws*)d_ws;
  float* out = (float*)d_out;
  hipLaunchKernelGGL(k_moments, dim3(NBC),       dim3(1024), 0, stream, f, ws);
  hipLaunchKernelGGL(k_top2,    dim3(K2_BLOCKS), dim3(256),  0, stream, f, ws);
  hipLaunchKernelGGL(k_fin,     dim3(1),         dim3(512),  0, stream, ws, out);
}